// Round 9
// baseline (113.810 us; speedup 1.0000x reference)
//
#include <hip/hip_runtime.h>
#include <hip/hip_bf16.h>

constexpr int B = 4;
constexpr int N = 50000;
constexpr int K = 128;
constexpr int S = 256;
constexpr int NCH = (N + 255) / 256;     // 196 chunks for error kernel (784 = 98*8 blocks)
constexpr int CH   = 64;                 // point chunks for the bucketed fit path
constexpr int CPTS = 782;                // points per chunk (64*782 = 50048 >= N)
constexpr int CAP  = 1024;               // bucket capacity (mean 512, sd 22 -> 22-sigma safe)
constexpr float EPS = 1e-5f;

__device__ __forceinline__ float frcp  (float x) { return __builtin_amdgcn_rcpf(x); }
__device__ __forceinline__ float frsq  (float x) { return __builtin_amdgcn_rsqf(x); }
__device__ __forceinline__ float fsqrt_(float x) { return __builtin_amdgcn_sqrtf(x); }

// ---------------------------------------------------------------------------
// Static-indexed Jacobi solve (registers only — rule #20)
// ---------------------------------------------------------------------------
template<int P, int Q>
__device__ __forceinline__ void rot(float (&A)[4][4], float (&V)[4][4])
{
  const float apq = A[P][Q];
  const float theta = 0.5f * (A[Q][Q] - A[P][P]) * frcp(apq);
  const float tt = copysignf(
      frcp(fabsf(theta) + fsqrt_(fmaf(theta, theta, 1.f))), theta);
  float c  = frsq(fmaf(tt, tt, 1.f));
  float sn = tt * c;
  const bool tiny = fabsf(apq) < 1e-20f;
  c  = tiny ? 1.f : c;
  sn = tiny ? 0.f : sn;
  #pragma unroll
  for (int i = 0; i < 4; ++i) {
    const float aip = A[i][P], aiq = A[i][Q];
    A[i][P] = c * aip - sn * aiq;
    A[i][Q] = sn * aip + c * aiq;
  }
  #pragma unroll
  for (int i = 0; i < 4; ++i) {
    const float api = A[P][i], aqi = A[Q][i];
    A[P][i] = c * api - sn * aqi;
    A[Q][i] = sn * api + c * aqi;
  }
  #pragma unroll
  for (int i = 0; i < 4; ++i) {
    const float vip = V[i][P], viq = V[i][Q];
    V[i][P] = c * vip - sn * viq;
    V[i][Q] = sn * vip + c * viq;
  }
}

// Sm = {W, Σwp(3), Σwq(3), Σw p⊗q(9)}  ->  write 4x4 transform at To
__device__ __forceinline__ void solve_and_write(const float (&Sm)[16], float* To)
{
  const float W   = Sm[0];
  const float inv = frcp(W + EPS);
  const float scx = Sm[1]*inv, scy = Sm[2]*inv, scz = Sm[3]*inv;
  const float tcx = Sm[4]*inv, tcy = Sm[5]*inv, tcz = Sm[6]*inv;
  const float f = 2.f - W * inv;     // H = Σ(w s⊗t)·inv − (2−σ)·sc⊗tc
  const float Sxx = Sm[7]*inv  - f*scx*tcx;
  const float Sxy = Sm[8]*inv  - f*scx*tcy;
  const float Sxz = Sm[9]*inv  - f*scx*tcz;
  const float Syx = Sm[10]*inv - f*scy*tcx;
  const float Syy = Sm[11]*inv - f*scy*tcy;
  const float Syz = Sm[12]*inv - f*scy*tcz;
  const float Szx = Sm[13]*inv - f*scz*tcx;
  const float Szy = Sm[14]*inv - f*scz*tcy;
  const float Szz = Sm[15]*inv - f*scz*tcz;

  float A[4][4], V[4][4];
  A[0][0] = Sxx + Syy + Szz;
  A[0][1] = Syz - Szy;  A[0][2] = Szx - Sxz;  A[0][3] = Sxy - Syx;
  A[1][1] = Sxx - Syy - Szz;
  A[1][2] = Sxy + Syx;  A[1][3] = Szx + Sxz;
  A[2][2] = -Sxx + Syy - Szz;
  A[2][3] = Syz + Szy;
  A[3][3] = -Sxx - Syy + Szz;
  A[1][0] = A[0][1]; A[2][0] = A[0][2]; A[3][0] = A[0][3];
  A[2][1] = A[1][2]; A[3][1] = A[1][3]; A[3][2] = A[2][3];

  #pragma unroll
  for (int i = 0; i < 4; ++i)
    #pragma unroll
    for (int j = 0; j < 4; ++j) V[i][j] = (i == j) ? 1.f : 0.f;

  #pragma unroll 1
  for (int sweep = 0; sweep < 5; ++sweep) {
    rot<0,1>(A, V); rot<0,2>(A, V); rot<0,3>(A, V);
    rot<1,2>(A, V); rot<1,3>(A, V); rot<2,3>(A, V);
  }

  const float d0 = A[0][0], d1 = A[1][1], d2 = A[2][2], d3 = A[3][3];
  const bool b1 = d1 > d0;
  const bool b3 = d3 > d2;
  const bool bb = (b3 ? d3 : d2) > (b1 ? d1 : d0);
  float qw  = bb ? (b3 ? V[0][3] : V[0][2]) : (b1 ? V[0][1] : V[0][0]);
  float qxv = bb ? (b3 ? V[1][3] : V[1][2]) : (b1 ? V[1][1] : V[1][0]);
  float qyv = bb ? (b3 ? V[2][3] : V[2][2]) : (b1 ? V[2][1] : V[2][0]);
  float qzv = bb ? (b3 ? V[3][3] : V[3][2]) : (b1 ? V[3][1] : V[3][0]);

  const float qn = frsq(qw*qw + qxv*qxv + qyv*qyv + qzv*qzv);
  qw *= qn; qxv *= qn; qyv *= qn; qzv *= qn;

  const float R00 = 1.f - 2.f*(qyv*qyv + qzv*qzv);
  const float R01 = 2.f*(qxv*qyv - qw*qzv);
  const float R02 = 2.f*(qxv*qzv + qw*qyv);
  const float R10 = 2.f*(qxv*qyv + qw*qzv);
  const float R11 = 1.f - 2.f*(qxv*qxv + qzv*qzv);
  const float R12 = 2.f*(qyv*qzv - qw*qxv);
  const float R20 = 2.f*(qxv*qzv - qw*qyv);
  const float R21 = 2.f*(qyv*qzv + qw*qxv);
  const float R22 = 1.f - 2.f*(qxv*qxv + qyv*qyv);

  const float tx = tcx - (R00*scx + R01*scy + R02*scz);
  const float ty = tcy - (R10*scx + R11*scy + R12*scz);
  const float tz = tcz - (R20*scx + R21*scy + R22*scz);

  float4* T4 = (float4*)To;
  T4[0] = make_float4(R00, R01, R02, tx);
  T4[1] = make_float4(R10, R11, R12, ty);
  T4[2] = make_float4(R20, R21, R22, tz);
  T4[3] = make_float4(0.f, 0.f, 0.f, 1.f);
}

// ---------------------------------------------------------------------------
// Kernel A: bucket sel entries by point-chunk. One linear pass over sel;
// entry (k,idx) -> bucket[idx/CPTS]. Packed u32 = (k<<16)|idx (idx<65536).
// Cursor atomics: 64 counters, ~512 increments each — cheap. Bucket order
// is nondeterministic; only effect is ~1e-6 FP jitter in moment sums
// (threshold 2e-2).
// ---------------------------------------------------------------------------
__global__ __launch_bounds__(256) void scatter_kernel(
    const int* __restrict__ sel, unsigned* __restrict__ bucket,
    int* __restrict__ cnt)
{
  const int e = blockIdx.x * 256 + threadIdx.x;   // [0, K*S)
  const int k   = e >> 8;                          // S = 256
  const int idx = sel[e];
  const int c   = idx / CPTS;
  const int slot = atomicAdd(&cnt[c], 1);
  if (slot < CAP)
    bucket[c * CAP + slot] = ((unsigned)k << 16) | (unsigned)idx;
}

// ---------------------------------------------------------------------------
// Kernel B: moments with ZERO scattered global access. Block = (b, chunk):
// stage the chunk's 782 points LINEARLY into LDS (few pages per block — no
// TLB thrash), then walk the chunk's ~512 bucket entries accumulating the 16
// weighted moments into per-k LDS rows via ds_add_f32. Rows padded to 17
// floats (gcd(17,32)=1) -> bank-conflict-free atomics. Writes 2048 partial
// floats per block, coalesced.
// ---------------------------------------------------------------------------
__global__ __launch_bounds__(256) void moment_kernel(
    const float* __restrict__ src, const float* __restrict__ tgt,
    const float* __restrict__ wts, const unsigned* __restrict__ bucket,
    const int* __restrict__ cnt, float* __restrict__ part)
{
  __shared__ float4 sp[CPTS];        // (p.xyz, w)
  __shared__ float4 sq[CPTS];        // (q.xyz, -)
  __shared__ float  mom[K * 17];     // padded per-k moment rows

  const int bid = blockIdx.x;        // 256 = 32*8 blocks
  const int xcd = bid & 7;
  const int b   = xcd >> 1;                        // batch pinned to XCD pair
  const int c   = ((bid >> 3) << 1) | (xcd & 1);   // bijective over [0,64)
  const int tid = threadIdx.x;

  const int lo = c * CPTS;
  const int cp = min(CPTS, N - lo);                // last chunk: 734

  for (int i = tid; i < cp; i += 256) {
    const int p = b * N + lo + i;
    sp[i] = make_float4(src[3*p], src[3*p+1], src[3*p+2], wts[p]);
    sq[i] = make_float4(tgt[3*p], tgt[3*p+1], tgt[3*p+2], 0.f);
  }
  for (int t = tid; t < K * 17; t += 256) mom[t] = 0.f;
  __syncthreads();

  const int nb = min(cnt[c], CAP);
  for (int e = tid; e < nb; e += 256) {
    const unsigned u = bucket[c * CAP + e];
    const int k = (int)(u >> 16);
    const int d = (int)(u & 0xFFFFu) - lo;
    const float4 P = sp[d];
    const float4 Q = sq[d];
    const float w = P.w;
    float* m = &mom[k * 17];
    atomicAdd(m + 0,  w);
    atomicAdd(m + 1,  w * P.x);
    atomicAdd(m + 2,  w * P.y);
    atomicAdd(m + 3,  w * P.z);
    atomicAdd(m + 4,  w * Q.x);
    atomicAdd(m + 5,  w * Q.y);
    atomicAdd(m + 6,  w * Q.z);
    const float wx = w * P.x, wy = w * P.y, wz = w * P.z;
    atomicAdd(m + 7,  wx * Q.x);
    atomicAdd(m + 8,  wx * Q.y);
    atomicAdd(m + 9,  wx * Q.z);
    atomicAdd(m + 10, wy * Q.x);
    atomicAdd(m + 11, wy * Q.y);
    atomicAdd(m + 12, wy * Q.z);
    atomicAdd(m + 13, wz * Q.x);
    atomicAdd(m + 14, wz * Q.y);
    atomicAdd(m + 15, wz * Q.z);
  }
  __syncthreads();

  float* out = part + (size_t)(b * CH + c) * (K * 16);
  for (int t = tid; t < K * 16; t += 256)
    out[t] = mom[(t >> 4) * 17 + (t & 15)];
}

// ---------------------------------------------------------------------------
// Kernel C: reduce chunk-partials (fixed order -> deterministic association)
// + fused static-register Jacobi solve. One block per (b,k).
// ---------------------------------------------------------------------------
__global__ __launch_bounds__(256) void reduce_solve_kernel(
    const float* __restrict__ part, float* __restrict__ T)
{
  const int bid = blockIdx.x;
  const int b   = bid >> 7;
  const int k   = bid & (K - 1);
  const int tid = threadIdx.x;
  const int i   = tid & 15;        // moment index
  const int sg  = tid >> 4;        // chunk group [0,16)

  float sum = 0.f;
  #pragma unroll
  for (int m = 0; m < CH / 16; ++m) {              // 4 independent loads
    const int c = sg + 16 * m;
    sum += part[(size_t)(b * CH + c) * (K * 16) + k * 16 + i];
  }

  __shared__ float red[16][17];
  red[sg][i] = sum;
  __syncthreads();

  __shared__ float SmS[16];
  if (tid < 16) {
    float t = 0.f;
    #pragma unroll
    for (int g = 0; g < 16; ++g) t += red[g][tid];
    SmS[tid] = t;
  }
  __syncthreads();

  if (tid == 0) {
    float Sm[16];
    #pragma unroll
    for (int z = 0; z < 16; ++z) Sm[z] = SmS[z];
    solve_and_write(Sm, T + (size_t)(b * K + k) * 16);
  }
}

// ---------------------------------------------------------------------------
// Fallback fit path (small-ws): R7's fused gather+solve
// ---------------------------------------------------------------------------
__global__ __launch_bounds__(256) void gather_solve_kernel(
    const float* __restrict__ src, const float* __restrict__ tgt,
    const float* __restrict__ wts, const int* __restrict__ sel,
    float* __restrict__ T)
{
  const int bid = blockIdx.x;
  const int xcd = bid & 7;
  const int b   = xcd >> 1;
  const int k   = ((bid >> 3) << 1) | (xcd & 1);
  const int s   = threadIdx.x;

  const int idx = sel[k * S + s];
  const float* ps = src + (size_t)(b * N + idx) * 3;
  const float* pt = tgt + (size_t)(b * N + idx) * 3;
  const float w  = wts[b * N + idx];
  const float px = ps[0], py = ps[1], pz = ps[2];
  const float qx = pt[0], qy = pt[1], qz = pt[2];

  float acc[16];
  acc[0] = w;
  acc[1] = w * px;  acc[2] = w * py;  acc[3] = w * pz;
  acc[4] = w * qx;  acc[5] = w * qy;  acc[6] = w * qz;
  acc[7]  = w * px * qx; acc[8]  = w * px * qy; acc[9]  = w * px * qz;
  acc[10] = w * py * qx; acc[11] = w * py * qy; acc[12] = w * py * qz;
  acc[13] = w * pz * qx; acc[14] = w * pz * qy; acc[15] = w * pz * qz;

  #pragma unroll
  for (int off = 32; off > 0; off >>= 1) {
    #pragma unroll
    for (int i = 0; i < 16; ++i)
      acc[i] += __shfl_down(acc[i], off);
  }

  __shared__ float red[4][16];
  const int lane = threadIdx.x & 63, wv = threadIdx.x >> 6;
  if (lane == 0) {
    #pragma unroll
    for (int i = 0; i < 16; ++i) red[wv][i] = acc[i];
  }
  __syncthreads();

  if (threadIdx.x == 0) {
    float Sm[16];
    #pragma unroll
    for (int i = 0; i < 16; ++i)
      Sm[i] = red[0][i] + red[1][i] + red[2][i] + red[3][i];
    solve_and_write(Sm, T + (size_t)(b * K + k) * 16);
  }
}

// ---------------------------------------------------------------------------
// Kernel D: error evaluation (R8 XCD-pinned version, unchanged)
// ---------------------------------------------------------------------------
constexpr int KPT = 4;
constexpr int KG  = K / KPT;      // 32
constexpr int NSL = 256 / KG;     // 8
constexpr int PPS = 256 / NSL;    // 32

__global__ __launch_bounds__(256) void error_kernel(
    const float* __restrict__ src, const float* __restrict__ tgt,
    const float* __restrict__ wts, const float* __restrict__ T,
    float* __restrict__ partial)
{
  __shared__ float4 sp[256];
  __shared__ float4 sq[256];
  __shared__ float  t4[K][12];
  __shared__ float  red[K][NSL + 1];

  const int bid = blockIdx.x;
  const int xcd = bid & 7;
  const int b   = xcd >> 1;
  const int ch  = ((bid >> 3) << 1) | (xcd & 1);
  const int tid = threadIdx.x;
  const int j   = ch * 256 + tid;

  float4 P = make_float4(0.f, 0.f, 0.f, 0.f);
  float4 Q = make_float4(0.f, 0.f, 0.f, 0.f);
  if (j < N) {
    const float* ps = src + (size_t)(b*N + j) * 3;
    const float* pt = tgt + (size_t)(b*N + j) * 3;
    P.x = ps[0]; P.y = ps[1]; P.z = ps[2]; P.w = wts[b*N + j];
    Q.x = pt[0]; Q.y = pt[1]; Q.z = pt[2];
  }
  sp[tid] = P; sq[tid] = Q;

  if (tid < K) {
    const float* tp = T + (size_t)(b*K + tid) * 16;
    #pragma unroll
    for (int c = 0; c < 12; ++c) t4[tid][c] = tp[c];
  }
  __syncthreads();

  const int kg    = tid & (KG - 1);
  const int slice = tid >> 5;

  float R[KPT][12];
  #pragma unroll
  for (int m = 0; m < KPT; ++m) {
    const int k = kg + m * KG;
    #pragma unroll
    for (int c = 0; c < 12; ++c) R[m][c] = t4[k][c];
  }

  float acc[KPT] = {0.f, 0.f, 0.f, 0.f};
  const int base = slice * PPS;
  #pragma unroll 4
  for (int i = 0; i < PPS; ++i) {
    const float4 p = sp[base + i];
    const float4 q = sq[base + i];
    #pragma unroll
    for (int m = 0; m < KPT; ++m) {
      const float dx = fmaf(R[m][0], p.x, fmaf(R[m][1], p.y, fmaf(R[m][2],  p.z, R[m][3])))  - q.x;
      const float dy = fmaf(R[m][4], p.x, fmaf(R[m][5], p.y, fmaf(R[m][6],  p.z, R[m][7])))  - q.y;
      const float dz = fmaf(R[m][8], p.x, fmaf(R[m][9], p.y, fmaf(R[m][10], p.z, R[m][11]))) - q.z;
      const float d2 = fmaf(dx, dx, fmaf(dy, dy, dz*dz));
      acc[m] = fmaf(p.w, fsqrt_(d2), acc[m]);
    }
  }

  #pragma unroll
  for (int m = 0; m < KPT; ++m)
    red[kg + m * KG][slice] = acc[m];
  __syncthreads();

  if (tid < K) {
    float sum = 0.f;
    #pragma unroll
    for (int s2 = 0; s2 < NSL; ++s2) sum += red[tid][s2];
    partial[((size_t)b * NCH + ch) * K + tid] = sum;
  }
}

// ---------------------------------------------------------------------------
// Kernel E: argmin (unchanged)
// ---------------------------------------------------------------------------
__global__ __launch_bounds__(256) void argmin_kernel(
    const float* __restrict__ partial, const float* __restrict__ T,
    float* __restrict__ out)
{
  const int b   = blockIdx.x;
  const int tid = threadIdx.x;
  const int k   = tid & (K - 1);
  const int h   = tid >> 7;

  float sum = 0.f;
  #pragma unroll 7
  for (int c = h; c < NCH; c += 2)
    sum += partial[((size_t)b * NCH + c) * K + k];

  __shared__ float vals[256];
  __shared__ int   idxs[K];
  vals[tid] = sum;
  __syncthreads();

  if (tid < K) { vals[tid] = vals[tid] + vals[tid + K]; idxs[tid] = tid; }
  __syncthreads();

  for (int off = K / 2; off > 0; off >>= 1) {
    if (tid < off) {
      const float o = vals[tid + off];
      if (o < vals[tid] || (o == vals[tid] && idxs[tid + off] < idxs[tid])) {
        vals[tid] = o; idxs[tid] = idxs[tid + off];
      }
    }
    __syncthreads();
  }

  const int best = idxs[0];
  if (tid < 16) out[(size_t)b * 16 + tid] = T[(size_t)(b * K + best) * 16 + tid];
}

// ---------------------------------------------------------------------------
extern "C" void kernel_launch(void* const* d_in, const int* in_sizes, int n_in,
                              void* d_out, int out_size, void* d_ws, size_t ws_size,
                              hipStream_t stream) {
  const float* src = (const float*)d_in[0];
  const float* tgt = (const float*)d_in[1];
  const float* wts = (const float*)d_in[2];
  const int*   sel = (const int*)d_in[3];

  // ws layout: cnt(256B) | bucket(256KB) | part(2MB) | T(32KB) | partial(400KB)
  const size_t cnt_bytes    = 256;
  const size_t bucket_bytes = (size_t)CH * CAP * 4;
  const size_t part_floats  = (size_t)B * CH * K * 16;
  const size_t T_floats     = (size_t)B * K * 16;
  const size_t partial_floats = (size_t)B * NCH * K;
  const size_t need = cnt_bytes + bucket_bytes +
      (part_floats + T_floats + partial_floats) * sizeof(float);

  if (ws_size >= need) {
    int*      cnt    = (int*)d_ws;
    unsigned* bucket = (unsigned*)((char*)d_ws + cnt_bytes);
    float*    part   = (float*)((char*)d_ws + cnt_bytes + bucket_bytes);
    float*    T      = part + part_floats;
    float*    partial = T + T_floats;

    hipMemsetAsync(cnt, 0, CH * sizeof(int), stream);
    scatter_kernel<<<(K * S) / 256, 256, 0, stream>>>(sel, bucket, cnt);
    moment_kernel<<<B * CH, 256, 0, stream>>>(src, tgt, wts, bucket, cnt, part);
    reduce_solve_kernel<<<B * K, 256, 0, stream>>>(part, T);
    error_kernel<<<B * NCH, 256, 0, stream>>>(src, tgt, wts, T, partial);
    argmin_kernel<<<B, 256, 0, stream>>>(partial, T, (float*)d_out);
  } else {
    float* T       = (float*)d_ws;
    float* partial = T + T_floats;

    gather_solve_kernel<<<B * K, 256, 0, stream>>>(src, tgt, wts, sel, T);
    error_kernel<<<B * NCH, 256, 0, stream>>>(src, tgt, wts, T, partial);
    argmin_kernel<<<B, 256, 0, stream>>>(partial, T, (float*)d_out);
  }
}

// Round 10
// 102.275 us; speedup vs baseline: 1.1128x; 1.1128x over previous
//
#include <hip/hip_runtime.h>
#include <hip/hip_bf16.h>

constexpr int B = 4;
constexpr int N = 50000;
constexpr int K = 128;
constexpr int S = 256;
constexpr int NCH = (N + 255) / 256;     // 196 chunks (784 = 98*8 blocks)
constexpr int NBLK = B * NCH;            // 784 error blocks
constexpr float EPS = 1e-5f;

__device__ __forceinline__ float frcp  (float x) { return __builtin_amdgcn_rcpf(x); }
__device__ __forceinline__ float frsq  (float x) { return __builtin_amdgcn_rsqf(x); }
__device__ __forceinline__ float fsqrt_(float x) { return __builtin_amdgcn_sqrtf(x); }

// ---------------------------------------------------------------------------
// Static-indexed Jacobi solve (registers only — rule #20)
// ---------------------------------------------------------------------------
template<int P, int Q>
__device__ __forceinline__ void rot(float (&A)[4][4], float (&V)[4][4])
{
  const float apq = A[P][Q];
  const float theta = 0.5f * (A[Q][Q] - A[P][P]) * frcp(apq);
  const float tt = copysignf(
      frcp(fabsf(theta) + fsqrt_(fmaf(theta, theta, 1.f))), theta);
  float c  = frsq(fmaf(tt, tt, 1.f));
  float sn = tt * c;
  const bool tiny = fabsf(apq) < 1e-20f;
  c  = tiny ? 1.f : c;
  sn = tiny ? 0.f : sn;
  #pragma unroll
  for (int i = 0; i < 4; ++i) {
    const float aip = A[i][P], aiq = A[i][Q];
    A[i][P] = c * aip - sn * aiq;
    A[i][Q] = sn * aip + c * aiq;
  }
  #pragma unroll
  for (int i = 0; i < 4; ++i) {
    const float api = A[P][i], aqi = A[Q][i];
    A[P][i] = c * api - sn * aqi;
    A[Q][i] = sn * api + c * aqi;
  }
  #pragma unroll
  for (int i = 0; i < 4; ++i) {
    const float vip = V[i][P], viq = V[i][Q];
    V[i][P] = c * vip - sn * viq;
    V[i][Q] = sn * vip + c * viq;
  }
}

// Sm = {W, Σwp(3), Σwq(3), Σw p⊗q(9)}  ->  write 4x4 transform at To
__device__ __forceinline__ void solve_and_write(const float (&Sm)[16], float* To)
{
  const float W   = Sm[0];
  const float inv = frcp(W + EPS);
  const float scx = Sm[1]*inv, scy = Sm[2]*inv, scz = Sm[3]*inv;
  const float tcx = Sm[4]*inv, tcy = Sm[5]*inv, tcz = Sm[6]*inv;
  const float f = 2.f - W * inv;     // H = Σ(w s⊗t)·inv − (2−σ)·sc⊗tc
  const float Sxx = Sm[7]*inv  - f*scx*tcx;
  const float Sxy = Sm[8]*inv  - f*scx*tcy;
  const float Sxz = Sm[9]*inv  - f*scx*tcz;
  const float Syx = Sm[10]*inv - f*scy*tcx;
  const float Syy = Sm[11]*inv - f*scy*tcy;
  const float Syz = Sm[12]*inv - f*scy*tcz;
  const float Szx = Sm[13]*inv - f*scz*tcx;
  const float Szy = Sm[14]*inv - f*scz*tcy;
  const float Szz = Sm[15]*inv - f*scz*tcz;

  float A[4][4], V[4][4];
  A[0][0] = Sxx + Syy + Szz;
  A[0][1] = Syz - Szy;  A[0][2] = Szx - Sxz;  A[0][3] = Sxy - Syx;
  A[1][1] = Sxx - Syy - Szz;
  A[1][2] = Sxy + Syx;  A[1][3] = Szx + Sxz;
  A[2][2] = -Sxx + Syy - Szz;
  A[2][3] = Syz + Szy;
  A[3][3] = -Sxx - Syy + Szz;
  A[1][0] = A[0][1]; A[2][0] = A[0][2]; A[3][0] = A[0][3];
  A[2][1] = A[1][2]; A[3][1] = A[1][3]; A[3][2] = A[2][3];

  #pragma unroll
  for (int i = 0; i < 4; ++i)
    #pragma unroll
    for (int j = 0; j < 4; ++j) V[i][j] = (i == j) ? 1.f : 0.f;

  #pragma unroll 1
  for (int sweep = 0; sweep < 5; ++sweep) {
    rot<0,1>(A, V); rot<0,2>(A, V); rot<0,3>(A, V);
    rot<1,2>(A, V); rot<1,3>(A, V); rot<2,3>(A, V);
  }

  const float d0 = A[0][0], d1 = A[1][1], d2 = A[2][2], d3 = A[3][3];
  const bool b1 = d1 > d0;
  const bool b3 = d3 > d2;
  const bool bb = (b3 ? d3 : d2) > (b1 ? d1 : d0);
  float qw  = bb ? (b3 ? V[0][3] : V[0][2]) : (b1 ? V[0][1] : V[0][0]);
  float qxv = bb ? (b3 ? V[1][3] : V[1][2]) : (b1 ? V[1][1] : V[1][0]);
  float qyv = bb ? (b3 ? V[2][3] : V[2][2]) : (b1 ? V[2][1] : V[2][0]);
  float qzv = bb ? (b3 ? V[3][3] : V[3][2]) : (b1 ? V[3][1] : V[3][0]);

  const float qn = frsq(qw*qw + qxv*qxv + qyv*qyv + qzv*qzv);
  qw *= qn; qxv *= qn; qyv *= qn; qzv *= qn;

  const float R00 = 1.f - 2.f*(qyv*qyv + qzv*qzv);
  const float R01 = 2.f*(qxv*qyv - qw*qzv);
  const float R02 = 2.f*(qxv*qzv + qw*qyv);
  const float R10 = 2.f*(qxv*qyv + qw*qzv);
  const float R11 = 1.f - 2.f*(qxv*qxv + qzv*qzv);
  const float R12 = 2.f*(qyv*qzv - qw*qxv);
  const float R20 = 2.f*(qxv*qzv - qw*qyv);
  const float R21 = 2.f*(qyv*qzv + qw*qxv);
  const float R22 = 1.f - 2.f*(qxv*qxv + qyv*qyv);

  const float tx = tcx - (R00*scx + R01*scy + R02*scz);
  const float ty = tcy - (R10*scx + R11*scy + R12*scz);
  const float tz = tcz - (R20*scx + R21*scy + R22*scz);

  float4* T4 = (float4*)To;
  T4[0] = make_float4(R00, R01, R02, tx);
  T4[1] = make_float4(R10, R11, R12, ty);
  T4[2] = make_float4(R20, R21, R22, tz);
  T4[3] = make_float4(0.f, 0.f, 0.f, 1.f);
}

// ---------------------------------------------------------------------------
// Kernel 1: fused fit kernel (R7-proven). Block = (b,k), XCD-pinned.
// Also zeroes the K2 ticket counter (deterministic per launch).
// ---------------------------------------------------------------------------
__global__ __launch_bounds__(256) void gather_solve_kernel(
    const float* __restrict__ src, const float* __restrict__ tgt,
    const float* __restrict__ wts, const int* __restrict__ sel,
    float* __restrict__ T, int* __restrict__ ticket)
{
  const int bid = blockIdx.x;
  if (bid == 0 && threadIdx.x == 0) *ticket = 0;   // visible to K2 at kernel boundary

  const int xcd = bid & 7;
  const int b   = xcd >> 1;                       // batch pinned to XCD pair
  const int k   = ((bid >> 3) << 1) | (xcd & 1);  // bijective over [0,128)
  const int s   = threadIdx.x;

  const int idx = sel[k * S + s];
  const float* ps = src + (size_t)(b * N + idx) * 3;
  const float* pt = tgt + (size_t)(b * N + idx) * 3;
  const float w  = wts[b * N + idx];
  const float px = ps[0], py = ps[1], pz = ps[2];
  const float qx = pt[0], qy = pt[1], qz = pt[2];

  float acc[16];
  acc[0] = w;
  acc[1] = w * px;  acc[2] = w * py;  acc[3] = w * pz;
  acc[4] = w * qx;  acc[5] = w * qy;  acc[6] = w * qz;
  acc[7]  = w * px * qx; acc[8]  = w * px * qy; acc[9]  = w * px * qz;
  acc[10] = w * py * qx; acc[11] = w * py * qy; acc[12] = w * py * qz;
  acc[13] = w * pz * qx; acc[14] = w * pz * qy; acc[15] = w * pz * qz;

  #pragma unroll
  for (int off = 32; off > 0; off >>= 1) {
    #pragma unroll
    for (int i = 0; i < 16; ++i)
      acc[i] += __shfl_down(acc[i], off);
  }

  __shared__ float red[4][16];
  const int lane = threadIdx.x & 63, wv = threadIdx.x >> 6;
  if (lane == 0) {
    #pragma unroll
    for (int i = 0; i < 16; ++i) red[wv][i] = acc[i];
  }
  __syncthreads();

  if (threadIdx.x == 0) {
    float Sm[16];
    #pragma unroll
    for (int i = 0; i < 16; ++i)
      Sm[i] = red[0][i] + red[1][i] + red[2][i] + red[3][i];
    solve_and_write(Sm, T + (size_t)(b * K + k) * 16);   // register-only solve
  }
}

// ---------------------------------------------------------------------------
// Kernel 2: error + FUSED argmin tail (last-block ticket; rocPRIM-style,
// deadlock-free: no block ever waits on another — the 784th block to
// finish performs the deterministic fixed-order reduce + argmin + output).
// Saves one dispatch (~8-10µs per the R9 scatter smoking-gun analysis).
// ---------------------------------------------------------------------------
constexpr int KPT = 4;
constexpr int KG  = K / KPT;      // 32
constexpr int NSL = 256 / KG;     // 8
constexpr int PPS = 256 / NSL;    // 32

__global__ __launch_bounds__(256) void error_argmin_kernel(
    const float* __restrict__ src, const float* __restrict__ tgt,
    const float* __restrict__ wts, const float* __restrict__ T,
    float* __restrict__ partial, int* __restrict__ ticket,
    float* __restrict__ out)
{
  __shared__ float4 sp[256];
  __shared__ float4 sq[256];
  __shared__ float  t4[K][12];
  __shared__ float  red[K][NSL + 1];
  __shared__ int    last;

  const int bid = blockIdx.x;
  const int xcd = bid & 7;
  const int b   = xcd >> 1;                        // batch pinned to XCD pair
  const int ch  = ((bid >> 3) << 1) | (xcd & 1);   // bijective over [0,196)
  const int tid = threadIdx.x;
  const int j   = ch * 256 + tid;

  float4 P = make_float4(0.f, 0.f, 0.f, 0.f);
  float4 Q = make_float4(0.f, 0.f, 0.f, 0.f);
  if (j < N) {
    const float* ps = src + (size_t)(b*N + j) * 3;
    const float* pt = tgt + (size_t)(b*N + j) * 3;
    P.x = ps[0]; P.y = ps[1]; P.z = ps[2]; P.w = wts[b*N + j];
    Q.x = pt[0]; Q.y = pt[1]; Q.z = pt[2];
  }
  sp[tid] = P; sq[tid] = Q;

  if (tid < K) {
    const float* tp = T + (size_t)(b*K + tid) * 16;
    #pragma unroll
    for (int c = 0; c < 12; ++c) t4[tid][c] = tp[c];
  }
  __syncthreads();

  const int kg    = tid & (KG - 1);
  const int slice = tid >> 5;

  float R[KPT][12];
  #pragma unroll
  for (int m = 0; m < KPT; ++m) {
    const int k = kg + m * KG;
    #pragma unroll
    for (int c = 0; c < 12; ++c) R[m][c] = t4[k][c];
  }

  float acc[KPT] = {0.f, 0.f, 0.f, 0.f};
  const int base = slice * PPS;
  #pragma unroll 4
  for (int i = 0; i < PPS; ++i) {
    const float4 p = sp[base + i];
    const float4 q = sq[base + i];
    #pragma unroll
    for (int m = 0; m < KPT; ++m) {
      const float dx = fmaf(R[m][0], p.x, fmaf(R[m][1], p.y, fmaf(R[m][2],  p.z, R[m][3])))  - q.x;
      const float dy = fmaf(R[m][4], p.x, fmaf(R[m][5], p.y, fmaf(R[m][6],  p.z, R[m][7])))  - q.y;
      const float dz = fmaf(R[m][8], p.x, fmaf(R[m][9], p.y, fmaf(R[m][10], p.z, R[m][11]))) - q.z;
      const float d2 = fmaf(dx, dx, fmaf(dy, dy, dz*dz));
      acc[m] = fmaf(p.w, fsqrt_(d2), acc[m]);
    }
  }

  #pragma unroll
  for (int m = 0; m < KPT; ++m)
    red[kg + m * KG][slice] = acc[m];
  __syncthreads();

  if (tid < K) {
    float sum = 0.f;
    #pragma unroll
    for (int s2 = 0; s2 < NSL; ++s2) sum += red[tid][s2];
    partial[((size_t)b * NCH + ch) * K + tid] = sum;
  }

  // ---- last-block argmin tail ----
  __threadfence();                       // release partials (device scope)
  if (tid == 0)
    last = (atomicAdd(ticket, 1) == NBLK - 1);
  __syncthreads();
  if (!last) return;
  __threadfence();                       // acquire all blocks' partials

  __shared__ float vals[256];
  __shared__ int   idxs[K];

  for (int bb = 0; bb < B; ++bb) {
    const int k = tid & (K - 1);
    const int h = tid >> 7;
    float sum = 0.f;
    #pragma unroll 7
    for (int c = h; c < NCH; c += 2)     // fixed-order partial sum
      sum += partial[((size_t)bb * NCH + c) * K + k];
    vals[tid] = sum;
    __syncthreads();

    if (tid < K) { vals[tid] = vals[tid] + vals[tid + K]; idxs[tid] = tid; }
    __syncthreads();

    for (int off = K / 2; off > 0; off >>= 1) {
      if (tid < off) {
        const float o = vals[tid + off];
        if (o < vals[tid] || (o == vals[tid] && idxs[tid + off] < idxs[tid])) {
          vals[tid] = o; idxs[tid] = idxs[tid + off];
        }
      }
      __syncthreads();
    }

    const int best = idxs[0];
    if (tid < 16)
      out[(size_t)bb * 16 + tid] = T[(size_t)(bb * K + best) * 16 + tid];
    __syncthreads();                      // vals/idxs reused next iteration
  }
}

// ---------------------------------------------------------------------------
extern "C" void kernel_launch(void* const* d_in, const int* in_sizes, int n_in,
                              void* d_out, int out_size, void* d_ws, size_t ws_size,
                              hipStream_t stream) {
  const float* src = (const float*)d_in[0];
  const float* tgt = (const float*)d_in[1];
  const float* wts = (const float*)d_in[2];
  const int*   sel = (const int*)d_in[3];

  float* T       = (float*)d_ws;                       // B*K*16 floats
  float* partial = T + (size_t)B * K * 16;             // B*NCH*K floats
  int*   ticket  = (int*)(partial + (size_t)B * NCH * K);

  gather_solve_kernel<<<B * K, 256, 0, stream>>>(src, tgt, wts, sel, T, ticket);
  error_argmin_kernel<<<B * NCH, 256, 0, stream>>>(
      src, tgt, wts, T, partial, ticket, (float*)d_out);
}

// Round 11
// 37.179 us; speedup vs baseline: 3.0612x; 2.7509x over previous
//
#include <hip/hip_runtime.h>
#include <hip/hip_bf16.h>

constexpr int B = 4;
constexpr int N = 50000;
constexpr int K = 128;
constexpr int S = 256;
constexpr int NCH = (N + 255) / 256;     // 196 chunks (784 = 98*8 blocks)
constexpr float EPS = 1e-5f;

__device__ __forceinline__ float frcp  (float x) { return __builtin_amdgcn_rcpf(x); }
__device__ __forceinline__ float frsq  (float x) { return __builtin_amdgcn_rsqf(x); }
__device__ __forceinline__ float fsqrt_(float x) { return __builtin_amdgcn_sqrtf(x); }

// ---------------------------------------------------------------------------
// Kernel 1: gather + moment reduce ONLY (solve removed — it was the silent
// scratch-spill hog: R8's VGPR_Count=52 cannot hold the ~60 live floats of
// the Jacobi tail, so A/V lived in scratch since R1; its serial scratch
// chain ~30µs was invariant to every gather restructure R3-R8).
// ---------------------------------------------------------------------------
__global__ __launch_bounds__(256) void gather_sums_kernel(
    const float* __restrict__ src, const float* __restrict__ tgt,
    const float* __restrict__ wts, const int* __restrict__ sel,
    float* __restrict__ sums)
{
  const int bid = blockIdx.x;
  const int xcd = bid & 7;
  const int b   = xcd >> 1;                       // batch pinned to XCD pair
  const int k   = ((bid >> 3) << 1) | (xcd & 1);  // bijective over [0,128)
  const int s   = threadIdx.x;

  const int idx = sel[k * S + s];
  const float* ps = src + (size_t)(b * N + idx) * 3;
  const float* pt = tgt + (size_t)(b * N + idx) * 3;
  const float w  = wts[b * N + idx];
  const float px = ps[0], py = ps[1], pz = ps[2];
  const float qx = pt[0], qy = pt[1], qz = pt[2];

  float acc[16];
  acc[0] = w;
  acc[1] = w * px;  acc[2] = w * py;  acc[3] = w * pz;
  acc[4] = w * qx;  acc[5] = w * qy;  acc[6] = w * qz;
  acc[7]  = w * px * qx; acc[8]  = w * px * qy; acc[9]  = w * px * qz;
  acc[10] = w * py * qx; acc[11] = w * py * qy; acc[12] = w * py * qz;
  acc[13] = w * pz * qx; acc[14] = w * pz * qy; acc[15] = w * pz * qz;

  #pragma unroll
  for (int off = 32; off > 0; off >>= 1) {
    #pragma unroll
    for (int i = 0; i < 16; ++i)
      acc[i] += __shfl_down(acc[i], off);
  }

  __shared__ float red[4][16];
  const int lane = threadIdx.x & 63, wv = threadIdx.x >> 6;
  if (lane == 0) {
    #pragma unroll
    for (int i = 0; i < 16; ++i) red[wv][i] = acc[i];
  }
  __syncthreads();

  if (threadIdx.x < 16) {
    const int i = threadIdx.x;
    sums[(size_t)(b * K + k) * 16 + i] =
        red[0][i] + red[1][i] + red[2][i] + red[3][i];
  }
}

// ---------------------------------------------------------------------------
// Scalar Jacobi rotation: every operand is a NAMED float reference — no
// arrays anywhere, so promotion to VGPRs is guaranteed (spill-proof).
// Symmetric A stored as upper triangle a00..a33 (10 scalars); V as 16.
// ---------------------------------------------------------------------------
__device__ __forceinline__ void jrot(
    float& app, float& apq, float& aqq,
    float& ar1p, float& ar1q,          // row i1: elements (i1,p),(i1,q)
    float& ar2p, float& ar2q,          // row i2
    float& v0p, float& v0q, float& v1p, float& v1q,
    float& v2p, float& v2q, float& v3p, float& v3q)
{
  const float theta = 0.5f * (aqq - app) * frcp(apq);
  const float tt = copysignf(
      frcp(fabsf(theta) + fsqrt_(fmaf(theta, theta, 1.f))), theta);
  float c  = frsq(fmaf(tt, tt, 1.f));
  float sn = tt * c;
  const bool tiny = fabsf(apq) < 1e-20f;
  c  = tiny ? 1.f : c;
  sn = tiny ? 0.f : sn;

  const float cc = c * c, ss = sn * sn, cs = c * sn;
  const float app_ = cc * app - 2.f * cs * apq + ss * aqq;
  const float aqq_ = ss * app + 2.f * cs * apq + cc * aqq;
  apq = (cc - ss) * apq + cs * (app - aqq);
  app = app_;  aqq = aqq_;

  float t;
  t = c * ar1p - sn * ar1q;  ar1q = sn * ar1p + c * ar1q;  ar1p = t;
  t = c * ar2p - sn * ar2q;  ar2q = sn * ar2p + c * ar2q;  ar2p = t;

  t = c * v0p - sn * v0q;  v0q = sn * v0p + c * v0q;  v0p = t;
  t = c * v1p - sn * v1q;  v1q = sn * v1p + c * v1q;  v1p = t;
  t = c * v2p - sn * v2q;  v2q = sn * v2p + c * v2q;  v2p = t;
  t = c * v3p - sn * v3q;  v3q = sn * v3p + c * v3q;  v3p = t;
}

// ---------------------------------------------------------------------------
// Kernel 2: solve. One LANE per (b,k); 8 blocks x 64 threads; all-scalar
// Horn-quaternion Jacobi -> guaranteed register-resident.
// ---------------------------------------------------------------------------
__global__ __launch_bounds__(64) void solve_kernel(
    const float* __restrict__ sums, float* __restrict__ T)
{
  const int bk = blockIdx.x * 64 + threadIdx.x;    // [0, 512)

  const float4* s4 = (const float4*)(sums + (size_t)bk * 16);
  const float4 sA = s4[0], sB = s4[1], sC = s4[2], sD = s4[3];

  const float W   = sA.x;
  const float inv = frcp(W + EPS);
  const float scx = sA.y * inv, scy = sA.z * inv, scz = sA.w * inv;
  const float tcx = sB.x * inv, tcy = sB.y * inv, tcz = sB.z * inv;
  const float f = 2.f - W * inv;       // H = Σ(w s⊗t)·inv − (2−σ)·sc⊗tc
  const float Sxx = sB.w * inv - f * scx * tcx;
  const float Sxy = sC.x * inv - f * scx * tcy;
  const float Sxz = sC.y * inv - f * scx * tcz;
  const float Syx = sC.z * inv - f * scy * tcx;
  const float Syy = sC.w * inv - f * scy * tcy;
  const float Syz = sD.x * inv - f * scy * tcz;
  const float Szx = sD.y * inv - f * scz * tcx;
  const float Szy = sD.z * inv - f * scz * tcy;
  const float Szz = sD.w * inv - f * scz * tcz;

  // Horn's 4x4 N matrix (symmetric upper triangle, named scalars)
  float a00 = Sxx + Syy + Szz;
  float a01 = Syz - Szy,  a02 = Szx - Sxz,  a03 = Sxy - Syx;
  float a11 = Sxx - Syy - Szz;
  float a12 = Sxy + Syx,  a13 = Szx + Sxz;
  float a22 = -Sxx + Syy - Szz;
  float a23 = Syz + Szy;
  float a33 = -Sxx - Syy + Szz;

  float v00 = 1.f, v01 = 0.f, v02 = 0.f, v03 = 0.f;
  float v10 = 0.f, v11 = 1.f, v12 = 0.f, v13 = 0.f;
  float v20 = 0.f, v21 = 0.f, v22 = 1.f, v23 = 0.f;
  float v30 = 0.f, v31 = 0.f, v32 = 0.f, v33 = 1.f;

  #pragma unroll 1
  for (int sweep = 0; sweep < 5; ++sweep) {
    // (p,q) = (0,1): other rows 2,3
    jrot(a00, a01, a11, a02, a12, a03, a13,
         v00, v01, v10, v11, v20, v21, v30, v31);
    // (0,2): other rows 1,3
    jrot(a00, a02, a22, a01, a12, a03, a23,
         v00, v02, v10, v12, v20, v22, v30, v32);
    // (0,3): other rows 1,2
    jrot(a00, a03, a33, a01, a13, a02, a23,
         v00, v03, v10, v13, v20, v23, v30, v33);
    // (1,2): other rows 0,3
    jrot(a11, a12, a22, a01, a02, a13, a23,
         v01, v02, v11, v12, v21, v22, v31, v32);
    // (1,3): other rows 0,2
    jrot(a11, a13, a33, a01, a03, a12, a23,
         v01, v03, v11, v13, v21, v23, v31, v33);
    // (2,3): other rows 0,1
    jrot(a22, a23, a33, a02, a03, a12, a13,
         v02, v03, v12, v13, v22, v23, v32, v33);
  }

  // branchless argmax of diagonal, select V column (all named scalars)
  const bool b1 = a11 > a00;
  const bool b3 = a33 > a22;
  const bool bb = (b3 ? a33 : a22) > (b1 ? a11 : a00);
  float qw  = bb ? (b3 ? v03 : v02) : (b1 ? v01 : v00);
  float qxv = bb ? (b3 ? v13 : v12) : (b1 ? v11 : v10);
  float qyv = bb ? (b3 ? v23 : v22) : (b1 ? v21 : v20);
  float qzv = bb ? (b3 ? v33 : v32) : (b1 ? v31 : v30);

  const float qn = frsq(qw*qw + qxv*qxv + qyv*qyv + qzv*qzv);
  qw *= qn; qxv *= qn; qyv *= qn; qzv *= qn;

  const float R00 = 1.f - 2.f*(qyv*qyv + qzv*qzv);
  const float R01 = 2.f*(qxv*qyv - qw*qzv);
  const float R02 = 2.f*(qxv*qzv + qw*qyv);
  const float R10 = 2.f*(qxv*qyv + qw*qzv);
  const float R11 = 1.f - 2.f*(qxv*qxv + qzv*qzv);
  const float R12 = 2.f*(qyv*qzv - qw*qxv);
  const float R20 = 2.f*(qxv*qzv - qw*qyv);
  const float R21 = 2.f*(qyv*qzv + qw*qxv);
  const float R22 = 1.f - 2.f*(qxv*qxv + qyv*qyv);

  const float tx = tcx - (R00*scx + R01*scy + R02*scz);
  const float ty = tcy - (R10*scx + R11*scy + R12*scz);
  const float tz = tcz - (R20*scx + R21*scy + R22*scz);

  float4* T4 = (float4*)(T + (size_t)bk * 16);
  T4[0] = make_float4(R00, R01, R02, tx);
  T4[1] = make_float4(R10, R11, R12, ty);
  T4[2] = make_float4(R20, R21, R22, tz);
  T4[3] = make_float4(0.f, 0.f, 0.f, 1.f);
}

// ---------------------------------------------------------------------------
// Kernel 3: error evaluation (R8 XCD-pinned version, unchanged)
// ---------------------------------------------------------------------------
constexpr int KPT = 4;
constexpr int KG  = K / KPT;      // 32
constexpr int NSL = 256 / KG;     // 8
constexpr int PPS = 256 / NSL;    // 32

__global__ __launch_bounds__(256) void error_kernel(
    const float* __restrict__ src, const float* __restrict__ tgt,
    const float* __restrict__ wts, const float* __restrict__ T,
    float* __restrict__ partial)
{
  __shared__ float4 sp[256];
  __shared__ float4 sq[256];
  __shared__ float  t4[K][12];
  __shared__ float  red[K][NSL + 1];

  const int bid = blockIdx.x;
  const int xcd = bid & 7;
  const int b   = xcd >> 1;
  const int ch  = ((bid >> 3) << 1) | (xcd & 1);
  const int tid = threadIdx.x;
  const int j   = ch * 256 + tid;

  float4 P = make_float4(0.f, 0.f, 0.f, 0.f);
  float4 Q = make_float4(0.f, 0.f, 0.f, 0.f);
  if (j < N) {
    const float* ps = src + (size_t)(b*N + j) * 3;
    const float* pt = tgt + (size_t)(b*N + j) * 3;
    P.x = ps[0]; P.y = ps[1]; P.z = ps[2]; P.w = wts[b*N + j];
    Q.x = pt[0]; Q.y = pt[1]; Q.z = pt[2];
  }
  sp[tid] = P; sq[tid] = Q;

  if (tid < K) {
    const float* tp = T + (size_t)(b*K + tid) * 16;
    #pragma unroll
    for (int c = 0; c < 12; ++c) t4[tid][c] = tp[c];
  }
  __syncthreads();

  const int kg    = tid & (KG - 1);
  const int slice = tid >> 5;

  float R[KPT][12];
  #pragma unroll
  for (int m = 0; m < KPT; ++m) {
    const int k = kg + m * KG;
    #pragma unroll
    for (int c = 0; c < 12; ++c) R[m][c] = t4[k][c];
  }

  float acc[KPT] = {0.f, 0.f, 0.f, 0.f};
  const int base = slice * PPS;
  #pragma unroll 4
  for (int i = 0; i < PPS; ++i) {
    const float4 p = sp[base + i];
    const float4 q = sq[base + i];
    #pragma unroll
    for (int m = 0; m < KPT; ++m) {
      const float dx = fmaf(R[m][0], p.x, fmaf(R[m][1], p.y, fmaf(R[m][2],  p.z, R[m][3])))  - q.x;
      const float dy = fmaf(R[m][4], p.x, fmaf(R[m][5], p.y, fmaf(R[m][6],  p.z, R[m][7])))  - q.y;
      const float dz = fmaf(R[m][8], p.x, fmaf(R[m][9], p.y, fmaf(R[m][10], p.z, R[m][11]))) - q.z;
      const float d2 = fmaf(dx, dx, fmaf(dy, dy, dz*dz));
      acc[m] = fmaf(p.w, fsqrt_(d2), acc[m]);
    }
  }

  #pragma unroll
  for (int m = 0; m < KPT; ++m)
    red[kg + m * KG][slice] = acc[m];
  __syncthreads();

  if (tid < K) {
    float sum = 0.f;
    #pragma unroll
    for (int s2 = 0; s2 < NSL; ++s2) sum += red[tid][s2];
    partial[((size_t)b * NCH + ch) * K + tid] = sum;
  }
}

// ---------------------------------------------------------------------------
// Kernel 4: argmin (unchanged)
// ---------------------------------------------------------------------------
__global__ __launch_bounds__(256) void argmin_kernel(
    const float* __restrict__ partial, const float* __restrict__ T,
    float* __restrict__ out)
{
  const int b   = blockIdx.x;
  const int tid = threadIdx.x;
  const int k   = tid & (K - 1);
  const int h   = tid >> 7;

  float sum = 0.f;
  #pragma unroll 7
  for (int c = h; c < NCH; c += 2)
    sum += partial[((size_t)b * NCH + c) * K + k];

  __shared__ float vals[256];
  __shared__ int   idxs[K];
  vals[tid] = sum;
  __syncthreads();

  if (tid < K) { vals[tid] = vals[tid] + vals[tid + K]; idxs[tid] = tid; }
  __syncthreads();

  for (int off = K / 2; off > 0; off >>= 1) {
    if (tid < off) {
      const float o = vals[tid + off];
      if (o < vals[tid] || (o == vals[tid] && idxs[tid + off] < idxs[tid])) {
        vals[tid] = o; idxs[tid] = idxs[tid + off];
      }
    }
    __syncthreads();
  }

  const int best = idxs[0];
  if (tid < 16) out[(size_t)b * 16 + tid] = T[(size_t)(b * K + best) * 16 + tid];
}

// ---------------------------------------------------------------------------
extern "C" void kernel_launch(void* const* d_in, const int* in_sizes, int n_in,
                              void* d_out, int out_size, void* d_ws, size_t ws_size,
                              hipStream_t stream) {
  const float* src = (const float*)d_in[0];
  const float* tgt = (const float*)d_in[1];
  const float* wts = (const float*)d_in[2];
  const int*   sel = (const int*)d_in[3];

  float* sums    = (float*)d_ws;                       // B*K*16 floats
  float* T       = sums + (size_t)B * K * 16;          // B*K*16 floats
  float* partial = T + (size_t)B * K * 16;             // B*NCH*K floats

  gather_sums_kernel<<<B * K, 256, 0, stream>>>(src, tgt, wts, sel, sums);
  solve_kernel<<<8, 64, 0, stream>>>(sums, T);
  error_kernel<<<B * NCH, 256, 0, stream>>>(src, tgt, wts, T, partial);
  argmin_kernel<<<B, 256, 0, stream>>>(partial, T, (float*)d_out);
}